// Round 20
// baseline (2198.364 us; speedup 1.0000x reference)
//
#include <hip/hip_runtime.h>
#include <math.h>

#define NC 10
#define KITERS 10
// B=8, S=4096, D=256, K=1024, tokens = 32768
// Bit-exact r10 decision semantics. r20: k_enh reverted to proven 256-thr 4x4
// tile (r15); k_assign 4-lanes-per-token (j-split of the 8-acc fold across a
// lane pair + IEEE-commutative shfl pair-adds -> identical dist bits);
// k_sums kept from r19. absmax must equal 0.001953125 exactly.

#define SWZ(row, q) ((q) ^ (((row) >> 2) & 15))

// ---------------- K1: sim + top5 + softmax + x_enh (r15 proven) ----------------
// 512 blocks x 256 thr; 64 tokens/block; chunk = 64 mem rows (16 chunks).
extern __shared__ float4 lds4[];  // 8192 float4 = 128 KB (dynamic)
__global__ __launch_bounds__(256, 1) void k_enh(const float* __restrict__ x,
                                                const float* __restrict__ mem,
                                                float* __restrict__ xenh) {
  float4* xt = lds4;          // 64 rows x 64 f4 (64 KB), swizzled
  float4* mt = lds4 + 4096;   // 64 rows x 64 f4 (64 KB), swizzled
  float* cv = (float*)lds4;             // [64][80]
  int*   ck = (int*)lds4 + 5120;        // [64][80]
  float* av = (float*)lds4 + 10240;     // [64][5]
  int*   ak = (int*)lds4 + 10560;       // [64][5]

  const int tid = threadIdx.x;
  const int tg = tid >> 4;
  const int kg = tid & 15;
  const int tokenBase = blockIdx.x * 64;

  {
    const float4* xg = (const float4*)(x + (size_t)tokenBase * 256);
    const float4* mg = (const float4*)mem;
#pragma unroll
    for (int i = 0; i < 16; ++i) {
      const int p = tid + 256 * i;
      const int row = p >> 6, q = p & 63;
      xt[row * 64 + SWZ(row, q)] = xg[p];
      mt[row * 64 + SWZ(row, q)] = mg[p];
    }
  }
  __syncthreads();

  float t5v[4][5]; int t5k[4][5];
#pragma unroll
  for (int i = 0; i < 4; ++i)
#pragma unroll
    for (int r = 0; r < 5; ++r) { t5v[i][r] = -INFINITY; t5k[i][r] = 0; }

  for (int kc = 0; kc < 16; ++kc) {
    float4 st[16];
    if (kc < 15) {
      const float4* mg = (const float4*)mem + (size_t)(kc + 1) * 4096;
#pragma unroll
      for (int i = 0; i < 16; ++i) st[i] = mg[tid + 256 * i];
    }

    float4 acc[4][4];
#pragma unroll
    for (int i = 0; i < 4; ++i)
#pragma unroll
      for (int j = 0; j < 4; ++j) acc[i][j] = make_float4(0.f, 0.f, 0.f, 0.f);

#pragma unroll 4
    for (int q = 0; q < 64; ++q) {
      float4 mv[4], xv[4];
#pragma unroll
      for (int j = 0; j < 4; ++j) {
        const int row = 4 * kg + j;
        mv[j] = mt[row * 64 + SWZ(row, q)];
      }
#pragma unroll
      for (int i = 0; i < 4; ++i) {
        const int row = 4 * tg + i;
        xv[i] = xt[row * 64 + SWZ(row, q)];
      }
#pragma unroll
      for (int i = 0; i < 4; ++i)
#pragma unroll
        for (int j = 0; j < 4; ++j) {
          acc[i][j].x = __fadd_rn(acc[i][j].x, __fmul_rn(xv[i].x, mv[j].x));
          acc[i][j].y = __fadd_rn(acc[i][j].y, __fmul_rn(xv[i].y, mv[j].y));
          acc[i][j].z = __fadd_rn(acc[i][j].z, __fmul_rn(xv[i].z, mv[j].z));
          acc[i][j].w = __fadd_rn(acc[i][j].w, __fmul_rn(xv[i].w, mv[j].w));
        }
    }

#pragma unroll
    for (int i = 0; i < 4; ++i)
#pragma unroll
      for (int j = 0; j < 4; ++j) {
        const float v = __fadd_rn(__fadd_rn(acc[i][j].x, acc[i][j].z),
                                  __fadd_rn(acc[i][j].y, acc[i][j].w));
        const int kk = kc * 64 + 4 * kg + j;
        if (v > t5v[i][4]) {
          t5v[i][4] = v; t5k[i][4] = kk;
          if (t5v[i][4] > t5v[i][3]) { float a = t5v[i][3]; t5v[i][3] = t5v[i][4]; t5v[i][4] = a; int ia = t5k[i][3]; t5k[i][3] = t5k[i][4]; t5k[i][4] = ia; }
          if (t5v[i][3] > t5v[i][2]) { float a = t5v[i][2]; t5v[i][2] = t5v[i][3]; t5v[i][3] = a; int ia = t5k[i][2]; t5k[i][2] = t5k[i][3]; t5k[i][3] = ia; }
          if (t5v[i][2] > t5v[i][1]) { float a = t5v[i][1]; t5v[i][1] = t5v[i][2]; t5v[i][2] = a; int ia = t5k[i][1]; t5k[i][1] = t5k[i][2]; t5k[i][2] = ia; }
          if (t5v[i][1] > t5v[i][0]) { float a = t5v[i][0]; t5v[i][0] = t5v[i][1]; t5v[i][1] = a; int ia = t5k[i][0]; t5k[i][0] = t5k[i][1]; t5k[i][1] = ia; }
        }
      }

    __syncthreads();
    if (kc < 15) {
#pragma unroll
      for (int i = 0; i < 16; ++i) {
        const int p = tid + 256 * i;
        const int row = p >> 6, q = p & 63;
        mt[row * 64 + SWZ(row, q)] = st[i];
      }
      __syncthreads();
    }
  }
  __syncthreads();

#pragma unroll
  for (int i = 0; i < 4; ++i) {
    const int token = 4 * tg + i;
#pragma unroll
    for (int r = 0; r < 5; ++r) {
      cv[token * 80 + kg * 5 + r] = t5v[i][r];
      ck[token * 80 + kg * 5 + r] = t5k[i][r];
    }
  }
  __syncthreads();

  if (tid < 64) {
    const int token = tid;
    float tv[5]; int tk[5];
#pragma unroll
    for (int r = 0; r < 5; ++r) {
      float best = -INFINITY; int bi = 0, bk = 0x7fffffff;
      for (int c = 0; c < 80; ++c) {
        const float vv = cv[token * 80 + c]; const int kkc = ck[token * 80 + c];
        if (vv > best || (vv == best && kkc < bk)) { best = vv; bi = c; bk = kkc; }
      }
      tv[r] = best; tk[r] = bk; cv[token * 80 + bi] = -INFINITY;
    }
    float mx = tv[0];
#pragma unroll
    for (int r = 1; r < 5; ++r) mx = fmaxf(mx, tv[r]);
    float e[5];
#pragma unroll
    for (int r = 0; r < 5; ++r)
      e[r] = (float)exp((double)__fsub_rn(tv[r], mx));
    float s = e[0];
#pragma unroll
    for (int r = 1; r < 5; ++r) s = __fadd_rn(s, e[r]);
#pragma unroll
    for (int r = 0; r < 5; ++r) { av[token * 5 + r] = __fdiv_rn(e[r], s); ak[token * 5 + r] = tk[r]; }
  }
  __syncthreads();

#pragma unroll
  for (int i = 0; i < 16; ++i) {
    const int flat = tid + 256 * i;
    const int token = flat >> 6, q = flat & 63;
    const float a0 = av[token * 5 + 0], a1 = av[token * 5 + 1], a2 = av[token * 5 + 2],
                a3 = av[token * 5 + 3], a4 = av[token * 5 + 4];
    const float4 xv = ((const float4*)(x + (size_t)(tokenBase + token) * 256))[q];
    const float4 m0 = ((const float4*)(mem + (size_t)ak[token * 5 + 0] * 256))[q];
    const float4 m1 = ((const float4*)(mem + (size_t)ak[token * 5 + 1] * 256))[q];
    const float4 m2 = ((const float4*)(mem + (size_t)ak[token * 5 + 2] * 256))[q];
    const float4 m3 = ((const float4*)(mem + (size_t)ak[token * 5 + 3] * 256))[q];
    const float4 m4 = ((const float4*)(mem + (size_t)ak[token * 5 + 4] * 256))[q];
    float4 o;
    {
      float ctx = __fmul_rn(a0, m0.x);
      ctx = __fadd_rn(ctx, __fmul_rn(a1, m1.x));
      ctx = __fadd_rn(ctx, __fmul_rn(a2, m2.x));
      ctx = __fadd_rn(ctx, __fmul_rn(a3, m3.x));
      ctx = __fadd_rn(ctx, __fmul_rn(a4, m4.x));
      o.x = __fadd_rn(xv.x, ctx);
    }
    {
      float ctx = __fmul_rn(a0, m0.y);
      ctx = __fadd_rn(ctx, __fmul_rn(a1, m1.y));
      ctx = __fadd_rn(ctx, __fmul_rn(a2, m2.y));
      ctx = __fadd_rn(ctx, __fmul_rn(a3, m3.y));
      ctx = __fadd_rn(ctx, __fmul_rn(a4, m4.y));
      o.y = __fadd_rn(xv.y, ctx);
    }
    {
      float ctx = __fmul_rn(a0, m0.z);
      ctx = __fadd_rn(ctx, __fmul_rn(a1, m1.z));
      ctx = __fadd_rn(ctx, __fmul_rn(a2, m2.z));
      ctx = __fadd_rn(ctx, __fmul_rn(a3, m3.z));
      ctx = __fadd_rn(ctx, __fmul_rn(a4, m4.z));
      o.z = __fadd_rn(xv.z, ctx);
    }
    {
      float ctx = __fmul_rn(a0, m0.w);
      ctx = __fadd_rn(ctx, __fmul_rn(a1, m1.w));
      ctx = __fadd_rn(ctx, __fmul_rn(a2, m2.w));
      ctx = __fadd_rn(ctx, __fmul_rn(a3, m3.w));
      ctx = __fadd_rn(ctx, __fmul_rn(a4, m4.w));
      o.w = __fadd_rn(xv.w, ctx);
    }
    ((float4*)(xenh + (size_t)tokenBase * 256))[flat] = o;
  }
}

// ---------------- zero the per-iteration count buffers ----------------
__global__ __launch_bounds__(256) void k_zero(int* __restrict__ p, int n) {
  const int i = blockIdx.x * 256 + threadIdx.x;
  if (i < n) p[i] = 0;
}

// ---------------- K3: init centroids (bit copy of x_enh rows) ----------------
__global__ __launch_bounds__(64) void k_init(const float* __restrict__ xenh,
                                             const int* __restrict__ init_idx,
                                             float* __restrict__ cent) {
  const int i = blockIdx.x;  // b*10 + j
  const int b = i / NC;
  const int s = init_idx[i];
  const int l = threadIdx.x;
  ((float4*)(cent + (size_t)i * 256))[l] =
      ((const float4*)(xenh + ((size_t)b * 4096 + s) * 256))[l];
}

// ---------------- K5: assignment -- 4 lanes per token ----------------
// 256 blocks x 512 thr; 128 tokens/block; sub = tid&3: h = sub>>1 (d-half),
// jh = sub&1 (accumulator-half j in {4jh..4jh+3}). Each r[j] stride-8 chain
// is whole on one lane (identical ops to r10); combine:
//   halfOwn = add(add(r0',r1'), add(r2',r3'))          (jh-local)
//   blk_h   = add(halfOwn, shfl_xor(halfOwn,1))        (== ((r0+r1)+(r2+r3))+((r4+..)))
//   dist    = add(blk_h, shfl_xor(blk_h,2))            (== add(blk0, blk1))
// IEEE fadd is bitwise commutative -> all 4 lanes identical dist -> same argmin.
__global__ __launch_bounds__(512) void k_assign(const float* __restrict__ xenh,
                                                const float* __restrict__ cent,
                                                int* __restrict__ assign,
                                                int* __restrict__ cnt) {
  __shared__ float cl[NC * 256];  // 10 KB
  const int tid = threadIdx.x;
  const int tokenBase = blockIdx.x * 128;
  const int b = blockIdx.x >> 5;    // 32 blocks per batch
  for (int i = tid; i < NC * 256; i += 512)
    cl[i] = cent[(size_t)b * NC * 256 + i];
  __syncthreads();

  const int token = tokenBase + (tid >> 2);
  const int sub = tid & 3;
  const int h = sub >> 1, jh = sub & 1;
  const int off = h * 128 + 4 * jh;           // float offset of this lane's j-quad
  const float* px = xenh + (size_t)token * 256 + off;
  const float* pc = cl + off;                 // + k*256

  float r4[NC][4];
  {  // i = 0: initialize the 4 owned chains
    const float4 p = *(const float4*)px;
    const float pj[4] = {p.x, p.y, p.z, p.w};
#pragma unroll
    for (int k = 0; k < NC; ++k) {
      const float4 c = *(const float4*)(pc + k * 256);
      const float cj[4] = {c.x, c.y, c.z, c.w};
#pragma unroll
      for (int jj = 0; jj < 4; ++jj) {
        const float d = __fsub_rn(pj[jj], cj[jj]);
        r4[k][jj] = __fmul_rn(d, d);
      }
    }
  }
#pragma unroll 5
  for (int i = 8; i < 128; i += 8) {
    const float4 p = *(const float4*)(px + i);
    const float pj[4] = {p.x, p.y, p.z, p.w};
#pragma unroll
    for (int k = 0; k < NC; ++k) {
      const float4 c = *(const float4*)(pc + k * 256 + i);
      const float cj[4] = {c.x, c.y, c.z, c.w};
#pragma unroll
      for (int jj = 0; jj < 4; ++jj) {
        const float d = __fsub_rn(pj[jj], cj[jj]);
        r4[k][jj] = __fadd_rn(r4[k][jj], __fmul_rn(d, d));
      }
    }
  }

  float best = INFINITY; int bk = 0;
#pragma unroll
  for (int k = 0; k < NC; ++k) {
    const float halfOwn = __fadd_rn(__fadd_rn(r4[k][0], r4[k][1]),
                                    __fadd_rn(r4[k][2], r4[k][3]));
    const float blk = __fadd_rn(halfOwn, __shfl_xor(halfOwn, 1));
    const float dist = __fadd_rn(blk, __shfl_xor(blk, 2));
    if (dist < best) { best = dist; bk = k; }
  }
  if (sub == 0) assign[token] = bk;
#pragma unroll
  for (int k = 0; k < NC; ++k) {
    const unsigned long long m =
        __ballot(bk == k) & 0x1111111111111111ULL;  // one lane per token
    if ((tid & 63) == 0) atomicAdd(&cnt[b * NC + k], (int)__popcll(m));
  }
}

// ---------------- K6: cluster sums -- r19 proven (320 blocks; 32-deep batches) ----------------
// Per-(k,d) chain strictly s-ascending with (a==k)?xe:+0.0 adds == r10 order.
__global__ __launch_bounds__(64) void k_sums(const float* __restrict__ xenh,
                                             const int* __restrict__ assign,
                                             const int* __restrict__ cnt,
                                             float* __restrict__ cent) {
  const int bid = blockIdx.x;        // 320 = 8b * 10k * 4 d-quarters
  const int b = bid / 40;
  const int rem = bid % 40;
  const int k = rem >> 2;
  const int d = (rem & 3) * 64 + threadIdx.x;
  const float* xb = xenh + (size_t)b * 4096 * 256 + d;
  const int* ab = assign + b * 4096;

  float acc = 0.0f;
  for (int c = 0; c < 128; ++c) {
    float xe[32]; int ar[32];
#pragma unroll
    for (int j = 0; j < 32; ++j) xe[j] = xb[(size_t)(c * 32 + j) * 256];
#pragma unroll
    for (int j = 0; j < 32; ++j) ar[j] = ab[c * 32 + j];
#pragma unroll
    for (int j = 0; j < 32; ++j)
      acc = __fadd_rn(acc, (ar[j] == k) ? xe[j] : 0.0f);
  }
  const int cc = cnt[b * NC + k];
  cent[((size_t)(b * NC + k)) * 256 + d] = (cc == 0) ? 0.0f : __fdiv_rn(acc, (float)cc);
}

// ---------------- K7: quantize ----------------
__global__ __launch_bounds__(256) void k_quant(const float* __restrict__ cent,
                                               const int* __restrict__ assign,
                                               float* __restrict__ out) {
  const int token = blockIdx.x * 4 + (threadIdx.x >> 6);
  const int l = threadIdx.x & 63;
  const int b = token >> 12;
  const int a = assign[token];
  ((float4*)out)[(size_t)token * 64 + l] =
      ((const float4*)cent)[(size_t)(b * NC + a) * 64 + l];
}

extern "C" void kernel_launch(void* const* d_in, const int* in_sizes, int n_in,
                              void* d_out, int out_size, void* d_ws, size_t ws_size,
                              hipStream_t stream) {
  const float* x = (const float*)d_in[0];      // [8,4096,256] f32
  const float* mem = (const float*)d_in[1];    // [1024,256] f32
  const int* init_idx = (const int*)d_in[2];   // [8,10] i32
  float* xenh = (float*)d_out;                 // x_enh materialized in d_out
  char* ws = (char*)d_ws;

  float* cent   = (float*)(ws);                //  81920 B
  int*   assign = (int*)  (ws + 81920);        // 131072 B
  int*   cntbuf = (int*)  (ws + 212992);       // KITERS*8*NC ints

  (void)hipFuncSetAttribute((const void*)k_enh,
                            hipFuncAttributeMaxDynamicSharedMemorySize, 131072);

  k_zero<<<4, 256, 0, stream>>>(cntbuf, KITERS * 8 * NC);
  k_enh<<<512, 256, 131072, stream>>>(x, mem, xenh);
  k_init<<<80, 64, 0, stream>>>(xenh, init_idx, cent);
  for (int it = 0; it < KITERS; ++it) {
    k_assign<<<256, 512, 0, stream>>>(xenh, cent, assign, cntbuf + it * 8 * NC);
    k_sums<<<320, 64, 0, stream>>>(xenh, assign, cntbuf + it * 8 * NC, cent);
  }
  k_quant<<<8192, 256, 0, stream>>>(cent, assign, (float*)d_out);
}

// Round 21
// 1942.188 us; speedup vs baseline: 1.1319x; 1.1319x over previous
//
#include <hip/hip_runtime.h>
#include <math.h>

#define NC 10
#define KITERS 10
// B=8, S=4096, D=256, K=1024, tokens = 32768
// Bit-exact r10 decision semantics. r21: k_assign = r18 2-lane contiguous fold
// + batch->XCD-pinned block mapping (XCD = bid%8 = batch) + full unroll;
// k_sums = r19 + same mapping. x_enh slice (4MB/batch) stays hot in its XCD's
// L2 across all iterations. absmax must equal 0.001953125 exactly.

#define SWZ(row, q) ((q) ^ (((row) >> 2) & 15))

// ---------------- K1: sim + top5 + softmax + x_enh (r15 proven) ----------------
extern __shared__ float4 lds4[];  // 8192 float4 = 128 KB (dynamic)
__global__ __launch_bounds__(256, 1) void k_enh(const float* __restrict__ x,
                                                const float* __restrict__ mem,
                                                float* __restrict__ xenh) {
  float4* xt = lds4;          // 64 rows x 64 f4 (64 KB), swizzled
  float4* mt = lds4 + 4096;   // 64 rows x 64 f4 (64 KB), swizzled
  float* cv = (float*)lds4;             // [64][80]
  int*   ck = (int*)lds4 + 5120;        // [64][80]
  float* av = (float*)lds4 + 10240;     // [64][5]
  int*   ak = (int*)lds4 + 10560;       // [64][5]

  const int tid = threadIdx.x;
  const int tg = tid >> 4;
  const int kg = tid & 15;
  const int tokenBase = blockIdx.x * 64;

  {
    const float4* xg = (const float4*)(x + (size_t)tokenBase * 256);
    const float4* mg = (const float4*)mem;
#pragma unroll
    for (int i = 0; i < 16; ++i) {
      const int p = tid + 256 * i;
      const int row = p >> 6, q = p & 63;
      xt[row * 64 + SWZ(row, q)] = xg[p];
      mt[row * 64 + SWZ(row, q)] = mg[p];
    }
  }
  __syncthreads();

  float t5v[4][5]; int t5k[4][5];
#pragma unroll
  for (int i = 0; i < 4; ++i)
#pragma unroll
    for (int r = 0; r < 5; ++r) { t5v[i][r] = -INFINITY; t5k[i][r] = 0; }

  for (int kc = 0; kc < 16; ++kc) {
    float4 st[16];
    if (kc < 15) {
      const float4* mg = (const float4*)mem + (size_t)(kc + 1) * 4096;
#pragma unroll
      for (int i = 0; i < 16; ++i) st[i] = mg[tid + 256 * i];
    }

    float4 acc[4][4];
#pragma unroll
    for (int i = 0; i < 4; ++i)
#pragma unroll
      for (int j = 0; j < 4; ++j) acc[i][j] = make_float4(0.f, 0.f, 0.f, 0.f);

#pragma unroll 4
    for (int q = 0; q < 64; ++q) {
      float4 mv[4], xv[4];
#pragma unroll
      for (int j = 0; j < 4; ++j) {
        const int row = 4 * kg + j;
        mv[j] = mt[row * 64 + SWZ(row, q)];
      }
#pragma unroll
      for (int i = 0; i < 4; ++i) {
        const int row = 4 * tg + i;
        xv[i] = xt[row * 64 + SWZ(row, q)];
      }
#pragma unroll
      for (int i = 0; i < 4; ++i)
#pragma unroll
        for (int j = 0; j < 4; ++j) {
          acc[i][j].x = __fadd_rn(acc[i][j].x, __fmul_rn(xv[i].x, mv[j].x));
          acc[i][j].y = __fadd_rn(acc[i][j].y, __fmul_rn(xv[i].y, mv[j].y));
          acc[i][j].z = __fadd_rn(acc[i][j].z, __fmul_rn(xv[i].z, mv[j].z));
          acc[i][j].w = __fadd_rn(acc[i][j].w, __fmul_rn(xv[i].w, mv[j].w));
        }
    }

#pragma unroll
    for (int i = 0; i < 4; ++i)
#pragma unroll
      for (int j = 0; j < 4; ++j) {
        const float v = __fadd_rn(__fadd_rn(acc[i][j].x, acc[i][j].z),
                                  __fadd_rn(acc[i][j].y, acc[i][j].w));
        const int kk = kc * 64 + 4 * kg + j;
        if (v > t5v[i][4]) {
          t5v[i][4] = v; t5k[i][4] = kk;
          if (t5v[i][4] > t5v[i][3]) { float a = t5v[i][3]; t5v[i][3] = t5v[i][4]; t5v[i][4] = a; int ia = t5k[i][3]; t5k[i][3] = t5k[i][4]; t5k[i][4] = ia; }
          if (t5v[i][3] > t5v[i][2]) { float a = t5v[i][2]; t5v[i][2] = t5v[i][3]; t5v[i][3] = a; int ia = t5k[i][2]; t5k[i][2] = t5k[i][3]; t5k[i][3] = ia; }
          if (t5v[i][2] > t5v[i][1]) { float a = t5v[i][1]; t5v[i][1] = t5v[i][2]; t5v[i][2] = a; int ia = t5k[i][1]; t5k[i][1] = t5k[i][2]; t5k[i][2] = ia; }
          if (t5v[i][1] > t5v[i][0]) { float a = t5v[i][0]; t5v[i][0] = t5v[i][1]; t5v[i][1] = a; int ia = t5k[i][0]; t5k[i][0] = t5k[i][1]; t5k[i][1] = ia; }
        }
      }

    __syncthreads();
    if (kc < 15) {
#pragma unroll
      for (int i = 0; i < 16; ++i) {
        const int p = tid + 256 * i;
        const int row = p >> 6, q = p & 63;
        mt[row * 64 + SWZ(row, q)] = st[i];
      }
      __syncthreads();
    }
  }
  __syncthreads();

#pragma unroll
  for (int i = 0; i < 4; ++i) {
    const int token = 4 * tg + i;
#pragma unroll
    for (int r = 0; r < 5; ++r) {
      cv[token * 80 + kg * 5 + r] = t5v[i][r];
      ck[token * 80 + kg * 5 + r] = t5k[i][r];
    }
  }
  __syncthreads();

  if (tid < 64) {
    const int token = tid;
    float tv[5]; int tk[5];
#pragma unroll
    for (int r = 0; r < 5; ++r) {
      float best = -INFINITY; int bi = 0, bk = 0x7fffffff;
      for (int c = 0; c < 80; ++c) {
        const float vv = cv[token * 80 + c]; const int kkc = ck[token * 80 + c];
        if (vv > best || (vv == best && kkc < bk)) { best = vv; bi = c; bk = kkc; }
      }
      tv[r] = best; tk[r] = bk; cv[token * 80 + bi] = -INFINITY;
    }
    float mx = tv[0];
#pragma unroll
    for (int r = 1; r < 5; ++r) mx = fmaxf(mx, tv[r]);
    float e[5];
#pragma unroll
    for (int r = 0; r < 5; ++r)
      e[r] = (float)exp((double)__fsub_rn(tv[r], mx));
    float s = e[0];
#pragma unroll
    for (int r = 1; r < 5; ++r) s = __fadd_rn(s, e[r]);
#pragma unroll
    for (int r = 0; r < 5; ++r) { av[token * 5 + r] = __fdiv_rn(e[r], s); ak[token * 5 + r] = tk[r]; }
  }
  __syncthreads();

#pragma unroll
  for (int i = 0; i < 16; ++i) {
    const int flat = tid + 256 * i;
    const int token = flat >> 6, q = flat & 63;
    const float a0 = av[token * 5 + 0], a1 = av[token * 5 + 1], a2 = av[token * 5 + 2],
                a3 = av[token * 5 + 3], a4 = av[token * 5 + 4];
    const float4 xv = ((const float4*)(x + (size_t)(tokenBase + token) * 256))[q];
    const float4 m0 = ((const float4*)(mem + (size_t)ak[token * 5 + 0] * 256))[q];
    const float4 m1 = ((const float4*)(mem + (size_t)ak[token * 5 + 1] * 256))[q];
    const float4 m2 = ((const float4*)(mem + (size_t)ak[token * 5 + 2] * 256))[q];
    const float4 m3 = ((const float4*)(mem + (size_t)ak[token * 5 + 3] * 256))[q];
    const float4 m4 = ((const float4*)(mem + (size_t)ak[token * 5 + 4] * 256))[q];
    float4 o;
    {
      float ctx = __fmul_rn(a0, m0.x);
      ctx = __fadd_rn(ctx, __fmul_rn(a1, m1.x));
      ctx = __fadd_rn(ctx, __fmul_rn(a2, m2.x));
      ctx = __fadd_rn(ctx, __fmul_rn(a3, m3.x));
      ctx = __fadd_rn(ctx, __fmul_rn(a4, m4.x));
      o.x = __fadd_rn(xv.x, ctx);
    }
    {
      float ctx = __fmul_rn(a0, m0.y);
      ctx = __fadd_rn(ctx, __fmul_rn(a1, m1.y));
      ctx = __fadd_rn(ctx, __fmul_rn(a2, m2.y));
      ctx = __fadd_rn(ctx, __fmul_rn(a3, m3.y));
      ctx = __fadd_rn(ctx, __fmul_rn(a4, m4.y));
      o.y = __fadd_rn(xv.y, ctx);
    }
    {
      float ctx = __fmul_rn(a0, m0.z);
      ctx = __fadd_rn(ctx, __fmul_rn(a1, m1.z));
      ctx = __fadd_rn(ctx, __fmul_rn(a2, m2.z));
      ctx = __fadd_rn(ctx, __fmul_rn(a3, m3.z));
      ctx = __fadd_rn(ctx, __fmul_rn(a4, m4.z));
      o.z = __fadd_rn(xv.z, ctx);
    }
    {
      float ctx = __fmul_rn(a0, m0.w);
      ctx = __fadd_rn(ctx, __fmul_rn(a1, m1.w));
      ctx = __fadd_rn(ctx, __fmul_rn(a2, m2.w));
      ctx = __fadd_rn(ctx, __fmul_rn(a3, m3.w));
      ctx = __fadd_rn(ctx, __fmul_rn(a4, m4.w));
      o.w = __fadd_rn(xv.w, ctx);
    }
    ((float4*)(xenh + (size_t)tokenBase * 256))[flat] = o;
  }
}

// ---------------- zero the per-iteration count buffers ----------------
__global__ __launch_bounds__(256) void k_zero(int* __restrict__ p, int n) {
  const int i = blockIdx.x * 256 + threadIdx.x;
  if (i < n) p[i] = 0;
}

// ---------------- K3: init centroids (bit copy of x_enh rows) ----------------
__global__ __launch_bounds__(64) void k_init(const float* __restrict__ xenh,
                                             const int* __restrict__ init_idx,
                                             float* __restrict__ cent) {
  const int i = blockIdx.x;  // b*10 + j
  const int b = i / NC;
  const int s = init_idx[i];
  const int l = threadIdx.x;
  ((float4*)(cent + (size_t)i * 256))[l] =
      ((const float4*)(xenh + ((size_t)b * 4096 + s) * 256))[l];
}

// ---------------- K5: assignment -- r18 2-lane fold; batch->XCD-pinned ----------------
// 256 blocks x 256 thr; bid = j*8 + b -> XCD(bid%8) = b for all of batch b's
// 32 blocks; token = b*4096 + j*128 + (tid>>1). Fold/combine chains bit-
// identical to r18/r10.
__global__ __launch_bounds__(256) void k_assign(const float* __restrict__ xenh,
                                                const float* __restrict__ cent,
                                                int* __restrict__ assign,
                                                int* __restrict__ cnt) {
  __shared__ float cl[NC * 256];  // 10 KB
  const int tid = threadIdx.x;
  const int b = blockIdx.x & 7;
  const int j = blockIdx.x >> 3;          // 0..31
  const int tokenBase = b * 4096 + j * 128;
  for (int i = tid; i < NC * 256; i += 256)
    cl[i] = cent[(size_t)b * NC * 256 + i];
  __syncthreads();

  const int token = tokenBase + (tid >> 1);
  const int h = tid & 1;
  const float* px = xenh + (size_t)token * 256 + h * 128;
  const float* pc = cl + h * 128;   // + k*256

  float r[NC][8];
  {  // batch i = 0: initialize all folds
    float p8[8];
#pragma unroll
    for (int jj = 0; jj < 8; ++jj) p8[jj] = px[jj];
#pragma unroll
    for (int k = 0; k < NC; ++k)
#pragma unroll
      for (int jj = 0; jj < 8; ++jj) {
        const float d = __fsub_rn(p8[jj], pc[k * 256 + jj]);
        r[k][jj] = __fmul_rn(d, d);
      }
  }
#pragma unroll
  for (int i = 8; i < 128; i += 8) {
    float p8[8];
#pragma unroll
    for (int jj = 0; jj < 8; ++jj) p8[jj] = px[i + jj];
#pragma unroll
    for (int k = 0; k < NC; ++k)
#pragma unroll
      for (int jj = 0; jj < 8; ++jj) {
        const float d = __fsub_rn(p8[jj], pc[k * 256 + i + jj]);
        r[k][jj] = __fadd_rn(r[k][jj], __fmul_rn(d, d));
      }
  }

  float best = INFINITY; int bk = 0;
#pragma unroll
  for (int k = 0; k < NC; ++k) {
    const float blkOwn =
        __fadd_rn(__fadd_rn(__fadd_rn(r[k][0], r[k][1]), __fadd_rn(r[k][2], r[k][3])),
                  __fadd_rn(__fadd_rn(r[k][4], r[k][5]), __fadd_rn(r[k][6], r[k][7])));
    const float blkOther = __shfl_xor(blkOwn, 1);
    const float dist = __fadd_rn(blkOwn, blkOther);
    if (dist < best) { best = dist; bk = k; }
  }
  if (h == 0) assign[token] = bk;
#pragma unroll
  for (int k = 0; k < NC; ++k) {
    const unsigned long long m =
        __ballot(bk == k) & 0x5555555555555555ULL;  // even lanes only
    if ((tid & 63) == 0) atomicAdd(&cnt[b * NC + k], (int)__popcll(m));
  }
}

// ---------------- K6: cluster sums -- r19 + batch->XCD-pinned mapping ----------------
// 320 blocks: b = bid&7 (XCD-pinned), rem = bid>>3: k = rem>>2, quarter = rem&3.
// Per-(k,d) chain strictly s-ascending with (a==k)?xe:+0.0 adds == r10 order.
__global__ __launch_bounds__(64) void k_sums(const float* __restrict__ xenh,
                                             const int* __restrict__ assign,
                                             const int* __restrict__ cnt,
                                             float* __restrict__ cent) {
  const int b = blockIdx.x & 7;
  const int rem = blockIdx.x >> 3;   // 0..39
  const int k = rem >> 2;
  const int d = (rem & 3) * 64 + threadIdx.x;
  const float* xb = xenh + (size_t)b * 4096 * 256 + d;
  const int* ab = assign + b * 4096;

  float acc = 0.0f;
  for (int c = 0; c < 128; ++c) {
    float xe[32]; int ar[32];
#pragma unroll
    for (int j = 0; j < 32; ++j) xe[j] = xb[(size_t)(c * 32 + j) * 256];
#pragma unroll
    for (int j = 0; j < 32; ++j) ar[j] = ab[c * 32 + j];
#pragma unroll
    for (int j = 0; j < 32; ++j)
      acc = __fadd_rn(acc, (ar[j] == k) ? xe[j] : 0.0f);
  }
  const int cc = cnt[b * NC + k];
  cent[((size_t)(b * NC + k)) * 256 + d] = (cc == 0) ? 0.0f : __fdiv_rn(acc, (float)cc);
}

// ---------------- K7: quantize ----------------
__global__ __launch_bounds__(256) void k_quant(const float* __restrict__ cent,
                                               const int* __restrict__ assign,
                                               float* __restrict__ out) {
  const int token = blockIdx.x * 4 + (threadIdx.x >> 6);
  const int l = threadIdx.x & 63;
  const int b = token >> 12;
  const int a = assign[token];
  ((float4*)out)[(size_t)token * 64 + l] =
      ((const float4*)cent)[(size_t)(b * NC + a) * 64 + l];
}

extern "C" void kernel_launch(void* const* d_in, const int* in_sizes, int n_in,
                              void* d_out, int out_size, void* d_ws, size_t ws_size,
                              hipStream_t stream) {
  const float* x = (const float*)d_in[0];      // [8,4096,256] f32
  const float* mem = (const float*)d_in[1];    // [1024,256] f32
  const int* init_idx = (const int*)d_in[2];   // [8,10] i32
  float* xenh = (float*)d_out;                 // x_enh materialized in d_out
  char* ws = (char*)d_ws;

  float* cent   = (float*)(ws);                //  81920 B
  int*   assign = (int*)  (ws + 81920);        // 131072 B
  int*   cntbuf = (int*)  (ws + 212992);       // KITERS*8*NC ints

  (void)hipFuncSetAttribute((const void*)k_enh,
                            hipFuncAttributeMaxDynamicSharedMemorySize, 131072);

  k_zero<<<4, 256, 0, stream>>>(cntbuf, KITERS * 8 * NC);
  k_enh<<<512, 256, 131072, stream>>>(x, mem, xenh);
  k_init<<<80, 64, 0, stream>>>(xenh, init_idx, cent);
  for (int it = 0; it < KITERS; ++it) {
    k_assign<<<256, 256, 0, stream>>>(xenh, cent, assign, cntbuf + it * 8 * NC);
    k_sums<<<320, 64, 0, stream>>>(xenh, assign, cntbuf + it * 8 * NC, cent);
  }
  k_quant<<<8192, 256, 0, stream>>>(cent, assign, (float*)d_out);
}

// Round 22
// 1826.315 us; speedup vs baseline: 1.2037x; 1.0634x over previous
//
#include <hip/hip_runtime.h>
#include <math.h>

#define NC 10
#define KITERS 10
// B=8, S=4096, D=256, K=1024, tokens = 32768
// Bit-exact r10 decision semantics. r22: k_assign float4 + depth-2 load
// pipeline (fold order identical); k_sums 64-deep batches (chain order
// identical). absmax must equal 0.001953125 exactly.

#define SWZ(row, q) ((q) ^ (((row) >> 2) & 15))

// ---------------- K1: sim + top5 + softmax + x_enh (r15 proven) ----------------
extern __shared__ float4 lds4[];  // 8192 float4 = 128 KB (dynamic)
__global__ __launch_bounds__(256, 1) void k_enh(const float* __restrict__ x,
                                                const float* __restrict__ mem,
                                                float* __restrict__ xenh) {
  float4* xt = lds4;          // 64 rows x 64 f4 (64 KB), swizzled
  float4* mt = lds4 + 4096;   // 64 rows x 64 f4 (64 KB), swizzled
  float* cv = (float*)lds4;             // [64][80]
  int*   ck = (int*)lds4 + 5120;        // [64][80]
  float* av = (float*)lds4 + 10240;     // [64][5]
  int*   ak = (int*)lds4 + 10560;       // [64][5]

  const int tid = threadIdx.x;
  const int tg = tid >> 4;
  const int kg = tid & 15;
  const int tokenBase = blockIdx.x * 64;

  {
    const float4* xg = (const float4*)(x + (size_t)tokenBase * 256);
    const float4* mg = (const float4*)mem;
#pragma unroll
    for (int i = 0; i < 16; ++i) {
      const int p = tid + 256 * i;
      const int row = p >> 6, q = p & 63;
      xt[row * 64 + SWZ(row, q)] = xg[p];
      mt[row * 64 + SWZ(row, q)] = mg[p];
    }
  }
  __syncthreads();

  float t5v[4][5]; int t5k[4][5];
#pragma unroll
  for (int i = 0; i < 4; ++i)
#pragma unroll
    for (int r = 0; r < 5; ++r) { t5v[i][r] = -INFINITY; t5k[i][r] = 0; }

  for (int kc = 0; kc < 16; ++kc) {
    float4 st[16];
    if (kc < 15) {
      const float4* mg = (const float4*)mem + (size_t)(kc + 1) * 4096;
#pragma unroll
      for (int i = 0; i < 16; ++i) st[i] = mg[tid + 256 * i];
    }

    float4 acc[4][4];
#pragma unroll
    for (int i = 0; i < 4; ++i)
#pragma unroll
      for (int j = 0; j < 4; ++j) acc[i][j] = make_float4(0.f, 0.f, 0.f, 0.f);

#pragma unroll 4
    for (int q = 0; q < 64; ++q) {
      float4 mv[4], xv[4];
#pragma unroll
      for (int j = 0; j < 4; ++j) {
        const int row = 4 * kg + j;
        mv[j] = mt[row * 64 + SWZ(row, q)];
      }
#pragma unroll
      for (int i = 0; i < 4; ++i) {
        const int row = 4 * tg + i;
        xv[i] = xt[row * 64 + SWZ(row, q)];
      }
#pragma unroll
      for (int i = 0; i < 4; ++i)
#pragma unroll
        for (int j = 0; j < 4; ++j) {
          acc[i][j].x = __fadd_rn(acc[i][j].x, __fmul_rn(xv[i].x, mv[j].x));
          acc[i][j].y = __fadd_rn(acc[i][j].y, __fmul_rn(xv[i].y, mv[j].y));
          acc[i][j].z = __fadd_rn(acc[i][j].z, __fmul_rn(xv[i].z, mv[j].z));
          acc[i][j].w = __fadd_rn(acc[i][j].w, __fmul_rn(xv[i].w, mv[j].w));
        }
    }

#pragma unroll
    for (int i = 0; i < 4; ++i)
#pragma unroll
      for (int j = 0; j < 4; ++j) {
        const float v = __fadd_rn(__fadd_rn(acc[i][j].x, acc[i][j].z),
                                  __fadd_rn(acc[i][j].y, acc[i][j].w));
        const int kk = kc * 64 + 4 * kg + j;
        if (v > t5v[i][4]) {
          t5v[i][4] = v; t5k[i][4] = kk;
          if (t5v[i][4] > t5v[i][3]) { float a = t5v[i][3]; t5v[i][3] = t5v[i][4]; t5v[i][4] = a; int ia = t5k[i][3]; t5k[i][3] = t5k[i][4]; t5k[i][4] = ia; }
          if (t5v[i][3] > t5v[i][2]) { float a = t5v[i][2]; t5v[i][2] = t5v[i][3]; t5v[i][3] = a; int ia = t5k[i][2]; t5k[i][2] = t5k[i][3]; t5k[i][3] = ia; }
          if (t5v[i][2] > t5v[i][1]) { float a = t5v[i][1]; t5v[i][1] = t5v[i][2]; t5v[i][2] = a; int ia = t5k[i][1]; t5k[i][1] = t5k[i][2]; t5k[i][2] = ia; }
          if (t5v[i][1] > t5v[i][0]) { float a = t5v[i][0]; t5v[i][0] = t5v[i][1]; t5v[i][1] = a; int ia = t5k[i][0]; t5k[i][0] = t5k[i][1]; t5k[i][1] = ia; }
        }
      }

    __syncthreads();
    if (kc < 15) {
#pragma unroll
      for (int i = 0; i < 16; ++i) {
        const int p = tid + 256 * i;
        const int row = p >> 6, q = p & 63;
        mt[row * 64 + SWZ(row, q)] = st[i];
      }
      __syncthreads();
    }
  }
  __syncthreads();

#pragma unroll
  for (int i = 0; i < 4; ++i) {
    const int token = 4 * tg + i;
#pragma unroll
    for (int r = 0; r < 5; ++r) {
      cv[token * 80 + kg * 5 + r] = t5v[i][r];
      ck[token * 80 + kg * 5 + r] = t5k[i][r];
    }
  }
  __syncthreads();

  if (tid < 64) {
    const int token = tid;
    float tv[5]; int tk[5];
#pragma unroll
    for (int r = 0; r < 5; ++r) {
      float best = -INFINITY; int bi = 0, bk = 0x7fffffff;
      for (int c = 0; c < 80; ++c) {
        const float vv = cv[token * 80 + c]; const int kkc = ck[token * 80 + c];
        if (vv > best || (vv == best && kkc < bk)) { best = vv; bi = c; bk = kkc; }
      }
      tv[r] = best; tk[r] = bk; cv[token * 80 + bi] = -INFINITY;
    }
    float mx = tv[0];
#pragma unroll
    for (int r = 1; r < 5; ++r) mx = fmaxf(mx, tv[r]);
    float e[5];
#pragma unroll
    for (int r = 0; r < 5; ++r)
      e[r] = (float)exp((double)__fsub_rn(tv[r], mx));
    float s = e[0];
#pragma unroll
    for (int r = 1; r < 5; ++r) s = __fadd_rn(s, e[r]);
#pragma unroll
    for (int r = 0; r < 5; ++r) { av[token * 5 + r] = __fdiv_rn(e[r], s); ak[token * 5 + r] = tk[r]; }
  }
  __syncthreads();

#pragma unroll
  for (int i = 0; i < 16; ++i) {
    const int flat = tid + 256 * i;
    const int token = flat >> 6, q = flat & 63;
    const float a0 = av[token * 5 + 0], a1 = av[token * 5 + 1], a2 = av[token * 5 + 2],
                a3 = av[token * 5 + 3], a4 = av[token * 5 + 4];
    const float4 xv = ((const float4*)(x + (size_t)(tokenBase + token) * 256))[q];
    const float4 m0 = ((const float4*)(mem + (size_t)ak[token * 5 + 0] * 256))[q];
    const float4 m1 = ((const float4*)(mem + (size_t)ak[token * 5 + 1] * 256))[q];
    const float4 m2 = ((const float4*)(mem + (size_t)ak[token * 5 + 2] * 256))[q];
    const float4 m3 = ((const float4*)(mem + (size_t)ak[token * 5 + 3] * 256))[q];
    const float4 m4 = ((const float4*)(mem + (size_t)ak[token * 5 + 4] * 256))[q];
    float4 o;
    {
      float ctx = __fmul_rn(a0, m0.x);
      ctx = __fadd_rn(ctx, __fmul_rn(a1, m1.x));
      ctx = __fadd_rn(ctx, __fmul_rn(a2, m2.x));
      ctx = __fadd_rn(ctx, __fmul_rn(a3, m3.x));
      ctx = __fadd_rn(ctx, __fmul_rn(a4, m4.x));
      o.x = __fadd_rn(xv.x, ctx);
    }
    {
      float ctx = __fmul_rn(a0, m0.y);
      ctx = __fadd_rn(ctx, __fmul_rn(a1, m1.y));
      ctx = __fadd_rn(ctx, __fmul_rn(a2, m2.y));
      ctx = __fadd_rn(ctx, __fmul_rn(a3, m3.y));
      ctx = __fadd_rn(ctx, __fmul_rn(a4, m4.y));
      o.y = __fadd_rn(xv.y, ctx);
    }
    {
      float ctx = __fmul_rn(a0, m0.z);
      ctx = __fadd_rn(ctx, __fmul_rn(a1, m1.z));
      ctx = __fadd_rn(ctx, __fmul_rn(a2, m2.z));
      ctx = __fadd_rn(ctx, __fmul_rn(a3, m3.z));
      ctx = __fadd_rn(ctx, __fmul_rn(a4, m4.z));
      o.z = __fadd_rn(xv.z, ctx);
    }
    {
      float ctx = __fmul_rn(a0, m0.w);
      ctx = __fadd_rn(ctx, __fmul_rn(a1, m1.w));
      ctx = __fadd_rn(ctx, __fmul_rn(a2, m2.w));
      ctx = __fadd_rn(ctx, __fmul_rn(a3, m3.w));
      ctx = __fadd_rn(ctx, __fmul_rn(a4, m4.w));
      o.w = __fadd_rn(xv.w, ctx);
    }
    ((float4*)(xenh + (size_t)tokenBase * 256))[flat] = o;
  }
}

// ---------------- zero the per-iteration count buffers ----------------
__global__ __launch_bounds__(256) void k_zero(int* __restrict__ p, int n) {
  const int i = blockIdx.x * 256 + threadIdx.x;
  if (i < n) p[i] = 0;
}

// ---------------- K3: init centroids (bit copy of x_enh rows) ----------------
__global__ __launch_bounds__(64) void k_init(const float* __restrict__ xenh,
                                             const int* __restrict__ init_idx,
                                             float* __restrict__ cent) {
  const int i = blockIdx.x;  // b*10 + j
  const int b = i / NC;
  const int s = init_idx[i];
  const int l = threadIdx.x;
  ((float4*)(cent + (size_t)i * 256))[l] =
      ((const float4*)(xenh + ((size_t)b * 4096 + s) * 256))[l];
}

// ---------------- K5: assignment -- float4 + depth-2 pipeline, 2 lanes/token ----------------
// 256 blocks x 256 thr; bid = j*8 + b (XCD-pinned). Fold order bit-identical
// to r18/r10; loads are bit-copies (float4 unpack).
__global__ __launch_bounds__(256) void k_assign(const float* __restrict__ xenh,
                                                const float* __restrict__ cent,
                                                int* __restrict__ assign,
                                                int* __restrict__ cnt) {
  __shared__ float cl[NC * 256];  // 10 KB
  const int tid = threadIdx.x;
  const int b = blockIdx.x & 7;
  const int j = blockIdx.x >> 3;          // 0..31
  const int tokenBase = b * 4096 + j * 128;
  for (int i = tid; i < NC * 256; i += 256)
    cl[i] = cent[(size_t)b * NC * 256 + i];
  __syncthreads();

  const int token = tokenBase + (tid >> 1);
  const int h = tid & 1;
  const float4* px4 = (const float4*)(xenh + (size_t)token * 256 + h * 128);
  const float* pc = cl + h * 128;   // + k*256

  float r[NC][8];
  float4 c0 = px4[0], c1 = px4[1];
#pragma unroll
  for (int ib = 0; ib < 16; ++ib) {
    float4 n0, n1;
    if (ib < 15) { n0 = px4[2 * ib + 2]; n1 = px4[2 * ib + 3]; }
    const float p8[8] = {c0.x, c0.y, c0.z, c0.w, c1.x, c1.y, c1.z, c1.w};
    const int i = ib * 8;
    if (ib == 0) {
#pragma unroll
      for (int k = 0; k < NC; ++k)
#pragma unroll
        for (int jj = 0; jj < 8; ++jj) {
          const float d = __fsub_rn(p8[jj], pc[k * 256 + jj]);
          r[k][jj] = __fmul_rn(d, d);
        }
    } else {
#pragma unroll
      for (int k = 0; k < NC; ++k)
#pragma unroll
        for (int jj = 0; jj < 8; ++jj) {
          const float d = __fsub_rn(p8[jj], pc[k * 256 + i + jj]);
          r[k][jj] = __fadd_rn(r[k][jj], __fmul_rn(d, d));
        }
    }
    c0 = n0; c1 = n1;  // rotate AFTER compute (r14 lesson)
  }

  float best = INFINITY; int bk = 0;
#pragma unroll
  for (int k = 0; k < NC; ++k) {
    const float blkOwn =
        __fadd_rn(__fadd_rn(__fadd_rn(r[k][0], r[k][1]), __fadd_rn(r[k][2], r[k][3])),
                  __fadd_rn(__fadd_rn(r[k][4], r[k][5]), __fadd_rn(r[k][6], r[k][7])));
    const float blkOther = __shfl_xor(blkOwn, 1);
    const float dist = __fadd_rn(blkOwn, blkOther);
    if (dist < best) { best = dist; bk = k; }
  }
  if (h == 0) assign[token] = bk;
#pragma unroll
  for (int k = 0; k < NC; ++k) {
    const unsigned long long m =
        __ballot(bk == k) & 0x5555555555555555ULL;  // even lanes only
    if ((tid & 63) == 0) atomicAdd(&cnt[b * NC + k], (int)__popcll(m));
  }
}

// ---------------- K6: cluster sums -- 320 blocks; 64-deep batches ----------------
// Per-(k,d) chain strictly s-ascending with (a==k)?xe:+0.0 adds == r10 order.
__global__ __launch_bounds__(64) void k_sums(const float* __restrict__ xenh,
                                             const int* __restrict__ assign,
                                             const int* __restrict__ cnt,
                                             float* __restrict__ cent) {
  const int b = blockIdx.x & 7;
  const int rem = blockIdx.x >> 3;   // 0..39
  const int k = rem >> 2;
  const int d = (rem & 3) * 64 + threadIdx.x;
  const float* xb = xenh + (size_t)b * 4096 * 256 + d;
  const int* ab = assign + b * 4096;

  float acc = 0.0f;
  for (int c = 0; c < 64; ++c) {
    float xe[64]; int ar[64];
#pragma unroll
    for (int j = 0; j < 64; ++j) xe[j] = xb[(size_t)(c * 64 + j) * 256];
#pragma unroll
    for (int j = 0; j < 64; ++j) ar[j] = ab[c * 64 + j];
#pragma unroll
    for (int j = 0; j < 64; ++j)
      acc = __fadd_rn(acc, (ar[j] == k) ? xe[j] : 0.0f);
  }
  const int cc = cnt[b * NC + k];
  cent[((size_t)(b * NC + k)) * 256 + d] = (cc == 0) ? 0.0f : __fdiv_rn(acc, (float)cc);
}

// ---------------- K7: quantize ----------------
__global__ __launch_bounds__(256) void k_quant(const float* __restrict__ cent,
                                               const int* __restrict__ assign,
                                               float* __restrict__ out) {
  const int token = blockIdx.x * 4 + (threadIdx.x >> 6);
  const int l = threadIdx.x & 63;
  const int b = token >> 12;
  const int a = assign[token];
  ((float4*)out)[(size_t)token * 64 + l] =
      ((const float4*)cent)[(size_t)(b * NC + a) * 64 + l];
}

extern "C" void kernel_launch(void* const* d_in, const int* in_sizes, int n_in,
                              void* d_out, int out_size, void* d_ws, size_t ws_size,
                              hipStream_t stream) {
  const float* x = (const float*)d_in[0];      // [8,4096,256] f32
  const float* mem = (const float*)d_in[1];    // [1024,256] f32
  const int* init_idx = (const int*)d_in[2];   // [8,10] i32
  float* xenh = (float*)d_out;                 // x_enh materialized in d_out
  char* ws = (char*)d_ws;

  float* cent   = (float*)(ws);                //  81920 B
  int*   assign = (int*)  (ws + 81920);        // 131072 B
  int*   cntbuf = (int*)  (ws + 212992);       // KITERS*8*NC ints

  (void)hipFuncSetAttribute((const void*)k_enh,
                            hipFuncAttributeMaxDynamicSharedMemorySize, 131072);

  k_zero<<<4, 256, 0, stream>>>(cntbuf, KITERS * 8 * NC);
  k_enh<<<512, 256, 131072, stream>>>(x, mem, xenh);
  k_init<<<80, 64, 0, stream>>>(xenh, init_idx, cent);
  for (int it = 0; it < KITERS; ++it) {
    k_assign<<<256, 256, 0, stream>>>(xenh, cent, assign, cntbuf + it * 8 * NC);
    k_sums<<<320, 64, 0, stream>>>(xenh, assign, cntbuf + it * 8 * NC, cent);
  }
  k_quant<<<8192, 256, 0, stream>>>(cent, assign, (float*)d_out);
}

// Round 23
// 1774.842 us; speedup vs baseline: 1.2386x; 1.0290x over previous
//
#include <hip/hip_runtime.h>
#include <math.h>

#define NC 10
#define KITERS 10
// B=8, S=4096, D=256, K=1024, tokens = 32768
// Bit-exact r10 decision semantics. r23: x_enh transposed once (bit copy) to
// xT[b][d][s] when ws_size >= 34MB -> k_sums chain becomes contiguous float4
// stream (same strict s-ascending op order). Fallback = r22 k_sums. k_assign
// prefetch depth 4. absmax must equal 0.001953125 exactly.

#define SWZ(row, q) ((q) ^ (((row) >> 2) & 15))

// ---------------- K1: sim + top5 + softmax + x_enh (r15 proven) ----------------
extern __shared__ float4 lds4[];  // 8192 float4 = 128 KB (dynamic)
__global__ __launch_bounds__(256, 1) void k_enh(const float* __restrict__ x,
                                                const float* __restrict__ mem,
                                                float* __restrict__ xenh) {
  float4* xt = lds4;          // 64 rows x 64 f4 (64 KB), swizzled
  float4* mt = lds4 + 4096;   // 64 rows x 64 f4 (64 KB), swizzled
  float* cv = (float*)lds4;             // [64][80]
  int*   ck = (int*)lds4 + 5120;        // [64][80]
  float* av = (float*)lds4 + 10240;     // [64][5]
  int*   ak = (int*)lds4 + 10560;       // [64][5]

  const int tid = threadIdx.x;
  const int tg = tid >> 4;
  const int kg = tid & 15;
  const int tokenBase = blockIdx.x * 64;

  {
    const float4* xg = (const float4*)(x + (size_t)tokenBase * 256);
    const float4* mg = (const float4*)mem;
#pragma unroll
    for (int i = 0; i < 16; ++i) {
      const int p = tid + 256 * i;
      const int row = p >> 6, q = p & 63;
      xt[row * 64 + SWZ(row, q)] = xg[p];
      mt[row * 64 + SWZ(row, q)] = mg[p];
    }
  }
  __syncthreads();

  float t5v[4][5]; int t5k[4][5];
#pragma unroll
  for (int i = 0; i < 4; ++i)
#pragma unroll
    for (int r = 0; r < 5; ++r) { t5v[i][r] = -INFINITY; t5k[i][r] = 0; }

  for (int kc = 0; kc < 16; ++kc) {
    float4 st[16];
    if (kc < 15) {
      const float4* mg = (const float4*)mem + (size_t)(kc + 1) * 4096;
#pragma unroll
      for (int i = 0; i < 16; ++i) st[i] = mg[tid + 256 * i];
    }

    float4 acc[4][4];
#pragma unroll
    for (int i = 0; i < 4; ++i)
#pragma unroll
      for (int j = 0; j < 4; ++j) acc[i][j] = make_float4(0.f, 0.f, 0.f, 0.f);

#pragma unroll 4
    for (int q = 0; q < 64; ++q) {
      float4 mv[4], xv[4];
#pragma unroll
      for (int j = 0; j < 4; ++j) {
        const int row = 4 * kg + j;
        mv[j] = mt[row * 64 + SWZ(row, q)];
      }
#pragma unroll
      for (int i = 0; i < 4; ++i) {
        const int row = 4 * tg + i;
        xv[i] = xt[row * 64 + SWZ(row, q)];
      }
#pragma unroll
      for (int i = 0; i < 4; ++i)
#pragma unroll
        for (int j = 0; j < 4; ++j) {
          acc[i][j].x = __fadd_rn(acc[i][j].x, __fmul_rn(xv[i].x, mv[j].x));
          acc[i][j].y = __fadd_rn(acc[i][j].y, __fmul_rn(xv[i].y, mv[j].y));
          acc[i][j].z = __fadd_rn(acc[i][j].z, __fmul_rn(xv[i].z, mv[j].z));
          acc[i][j].w = __fadd_rn(acc[i][j].w, __fmul_rn(xv[i].w, mv[j].w));
        }
    }

#pragma unroll
    for (int i = 0; i < 4; ++i)
#pragma unroll
      for (int j = 0; j < 4; ++j) {
        const float v = __fadd_rn(__fadd_rn(acc[i][j].x, acc[i][j].z),
                                  __fadd_rn(acc[i][j].y, acc[i][j].w));
        const int kk = kc * 64 + 4 * kg + j;
        if (v > t5v[i][4]) {
          t5v[i][4] = v; t5k[i][4] = kk;
          if (t5v[i][4] > t5v[i][3]) { float a = t5v[i][3]; t5v[i][3] = t5v[i][4]; t5v[i][4] = a; int ia = t5k[i][3]; t5k[i][3] = t5k[i][4]; t5k[i][4] = ia; }
          if (t5v[i][3] > t5v[i][2]) { float a = t5v[i][2]; t5v[i][2] = t5v[i][3]; t5v[i][3] = a; int ia = t5k[i][2]; t5k[i][2] = t5k[i][3]; t5k[i][3] = ia; }
          if (t5v[i][2] > t5v[i][1]) { float a = t5v[i][1]; t5v[i][1] = t5v[i][2]; t5v[i][2] = a; int ia = t5k[i][1]; t5k[i][1] = t5k[i][2]; t5k[i][2] = ia; }
          if (t5v[i][1] > t5v[i][0]) { float a = t5v[i][0]; t5v[i][0] = t5v[i][1]; t5v[i][1] = a; int ia = t5k[i][0]; t5k[i][0] = t5k[i][1]; t5k[i][1] = ia; }
        }
      }

    __syncthreads();
    if (kc < 15) {
#pragma unroll
      for (int i = 0; i < 16; ++i) {
        const int p = tid + 256 * i;
        const int row = p >> 6, q = p & 63;
        mt[row * 64 + SWZ(row, q)] = st[i];
      }
      __syncthreads();
    }
  }
  __syncthreads();

#pragma unroll
  for (int i = 0; i < 4; ++i) {
    const int token = 4 * tg + i;
#pragma unroll
    for (int r = 0; r < 5; ++r) {
      cv[token * 80 + kg * 5 + r] = t5v[i][r];
      ck[token * 80 + kg * 5 + r] = t5k[i][r];
    }
  }
  __syncthreads();

  if (tid < 64) {
    const int token = tid;
    float tv[5]; int tk[5];
#pragma unroll
    for (int r = 0; r < 5; ++r) {
      float best = -INFINITY; int bi = 0, bk = 0x7fffffff;
      for (int c = 0; c < 80; ++c) {
        const float vv = cv[token * 80 + c]; const int kkc = ck[token * 80 + c];
        if (vv > best || (vv == best && kkc < bk)) { best = vv; bi = c; bk = kkc; }
      }
      tv[r] = best; tk[r] = bk; cv[token * 80 + bi] = -INFINITY;
    }
    float mx = tv[0];
#pragma unroll
    for (int r = 1; r < 5; ++r) mx = fmaxf(mx, tv[r]);
    float e[5];
#pragma unroll
    for (int r = 0; r < 5; ++r)
      e[r] = (float)exp((double)__fsub_rn(tv[r], mx));
    float s = e[0];
#pragma unroll
    for (int r = 1; r < 5; ++r) s = __fadd_rn(s, e[r]);
#pragma unroll
    for (int r = 0; r < 5; ++r) { av[token * 5 + r] = __fdiv_rn(e[r], s); ak[token * 5 + r] = tk[r]; }
  }
  __syncthreads();

#pragma unroll
  for (int i = 0; i < 16; ++i) {
    const int flat = tid + 256 * i;
    const int token = flat >> 6, q = flat & 63;
    const float a0 = av[token * 5 + 0], a1 = av[token * 5 + 1], a2 = av[token * 5 + 2],
                a3 = av[token * 5 + 3], a4 = av[token * 5 + 4];
    const float4 xv = ((const float4*)(x + (size_t)(tokenBase + token) * 256))[q];
    const float4 m0 = ((const float4*)(mem + (size_t)ak[token * 5 + 0] * 256))[q];
    const float4 m1 = ((const float4*)(mem + (size_t)ak[token * 5 + 1] * 256))[q];
    const float4 m2 = ((const float4*)(mem + (size_t)ak[token * 5 + 2] * 256))[q];
    const float4 m3 = ((const float4*)(mem + (size_t)ak[token * 5 + 3] * 256))[q];
    const float4 m4 = ((const float4*)(mem + (size_t)ak[token * 5 + 4] * 256))[q];
    float4 o;
    {
      float ctx = __fmul_rn(a0, m0.x);
      ctx = __fadd_rn(ctx, __fmul_rn(a1, m1.x));
      ctx = __fadd_rn(ctx, __fmul_rn(a2, m2.x));
      ctx = __fadd_rn(ctx, __fmul_rn(a3, m3.x));
      ctx = __fadd_rn(ctx, __fmul_rn(a4, m4.x));
      o.x = __fadd_rn(xv.x, ctx);
    }
    {
      float ctx = __fmul_rn(a0, m0.y);
      ctx = __fadd_rn(ctx, __fmul_rn(a1, m1.y));
      ctx = __fadd_rn(ctx, __fmul_rn(a2, m2.y));
      ctx = __fadd_rn(ctx, __fmul_rn(a3, m3.y));
      ctx = __fadd_rn(ctx, __fmul_rn(a4, m4.y));
      o.y = __fadd_rn(xv.y, ctx);
    }
    {
      float ctx = __fmul_rn(a0, m0.z);
      ctx = __fadd_rn(ctx, __fmul_rn(a1, m1.z));
      ctx = __fadd_rn(ctx, __fmul_rn(a2, m2.z));
      ctx = __fadd_rn(ctx, __fmul_rn(a3, m3.z));
      ctx = __fadd_rn(ctx, __fmul_rn(a4, m4.z));
      o.z = __fadd_rn(xv.z, ctx);
    }
    {
      float ctx = __fmul_rn(a0, m0.w);
      ctx = __fadd_rn(ctx, __fmul_rn(a1, m1.w));
      ctx = __fadd_rn(ctx, __fmul_rn(a2, m2.w));
      ctx = __fadd_rn(ctx, __fmul_rn(a3, m3.w));
      ctx = __fadd_rn(ctx, __fmul_rn(a4, m4.w));
      o.w = __fadd_rn(xv.w, ctx);
    }
    ((float4*)(xenh + (size_t)tokenBase * 256))[flat] = o;
  }
}

// ---------------- transpose x_enh -> xT[b][d][s] (bit copy) ----------------
__global__ __launch_bounds__(256) void k_transpose_x(const float* __restrict__ in,
                                                     float* __restrict__ outT) {
  __shared__ float t[32][33];
  const int tx = threadIdx.x & 31, ty = threadIdx.x >> 5;  // 32x8
  const int s0 = blockIdx.x * 32, d0 = blockIdx.y * 32, b = blockIdx.z;
  const float* ib = in + (size_t)b * 4096 * 256;
  float* ob = outT + (size_t)b * 256 * 4096;
#pragma unroll
  for (int i = 0; i < 4; ++i)
    t[ty + 8 * i][tx] = ib[(size_t)(s0 + ty + 8 * i) * 256 + d0 + tx];
  __syncthreads();
#pragma unroll
  for (int i = 0; i < 4; ++i)
    ob[(size_t)(d0 + ty + 8 * i) * 4096 + s0 + tx] = t[tx][ty + 8 * i];
}

// ---------------- zero the per-iteration count buffers ----------------
__global__ __launch_bounds__(256) void k_zero(int* __restrict__ p, int n) {
  const int i = blockIdx.x * 256 + threadIdx.x;
  if (i < n) p[i] = 0;
}

// ---------------- K3: init centroids (bit copy of x_enh rows) ----------------
__global__ __launch_bounds__(64) void k_init(const float* __restrict__ xenh,
                                             const int* __restrict__ init_idx,
                                             float* __restrict__ cent) {
  const int i = blockIdx.x;  // b*10 + j
  const int b = i / NC;
  const int s = init_idx[i];
  const int l = threadIdx.x;
  ((float4*)(cent + (size_t)i * 256))[l] =
      ((const float4*)(xenh + ((size_t)b * 4096 + s) * 256))[l];
}

// ---------------- K5: assignment -- float4 + depth-4 pipeline, 2 lanes/token ----------------
__global__ __launch_bounds__(256) void k_assign(const float* __restrict__ xenh,
                                                const float* __restrict__ cent,
                                                int* __restrict__ assign,
                                                int* __restrict__ cnt) {
  __shared__ float cl[NC * 256];  // 10 KB
  const int tid = threadIdx.x;
  const int b = blockIdx.x & 7;
  const int j = blockIdx.x >> 3;          // 0..31
  const int tokenBase = b * 4096 + j * 128;
  for (int i = tid; i < NC * 256; i += 256)
    cl[i] = cent[(size_t)b * NC * 256 + i];
  __syncthreads();

  const int token = tokenBase + (tid >> 1);
  const int h = tid & 1;
  const float4* px4 = (const float4*)(xenh + (size_t)token * 256 + h * 128);
  const float* pc = cl + h * 128;   // + k*256

  float r[NC][8];
  float4 c0 = px4[0], c1 = px4[1];
  float4 d0_ = px4[2], d1_ = px4[3];
#pragma unroll
  for (int ib = 0; ib < 16; ++ib) {
    float4 e0, e1;
    if (ib < 14) { e0 = px4[2 * ib + 4]; e1 = px4[2 * ib + 5]; }
    const float p8[8] = {c0.x, c0.y, c0.z, c0.w, c1.x, c1.y, c1.z, c1.w};
    const int i = ib * 8;
    if (ib == 0) {
#pragma unroll
      for (int k = 0; k < NC; ++k)
#pragma unroll
        for (int jj = 0; jj < 8; ++jj) {
          const float d = __fsub_rn(p8[jj], pc[k * 256 + jj]);
          r[k][jj] = __fmul_rn(d, d);
        }
    } else {
#pragma unroll
      for (int k = 0; k < NC; ++k)
#pragma unroll
        for (int jj = 0; jj < 8; ++jj) {
          const float d = __fsub_rn(p8[jj], pc[k * 256 + i + jj]);
          r[k][jj] = __fadd_rn(r[k][jj], __fmul_rn(d, d));
        }
    }
    c0 = d0_; c1 = d1_; d0_ = e0; d1_ = e1;  // rotate AFTER compute
  }

  float best = INFINITY; int bk = 0;
#pragma unroll
  for (int k = 0; k < NC; ++k) {
    const float blkOwn =
        __fadd_rn(__fadd_rn(__fadd_rn(r[k][0], r[k][1]), __fadd_rn(r[k][2], r[k][3])),
                  __fadd_rn(__fadd_rn(r[k][4], r[k][5]), __fadd_rn(r[k][6], r[k][7])));
    const float blkOther = __shfl_xor(blkOwn, 1);
    const float dist = __fadd_rn(blkOwn, blkOther);
    if (dist < best) { best = dist; bk = k; }
  }
  if (h == 0) assign[token] = bk;
#pragma unroll
  for (int k = 0; k < NC; ++k) {
    const unsigned long long m =
        __ballot(bk == k) & 0x5555555555555555ULL;  // even lanes only
    if ((tid & 63) == 0) atomicAdd(&cnt[b * NC + k], (int)__popcll(m));
  }
}

// ---------------- K6a: cluster sums from xT (contiguous float4 stream) ----------------
// Per-(k,d) chain strictly s-ascending (chunk c, quad j, elems x,y,z,w) == r10.
__global__ __launch_bounds__(64) void k_sums_T(const float* __restrict__ xT,
                                               const int* __restrict__ assign,
                                               const int* __restrict__ cnt,
                                               float* __restrict__ cent) {
  const int b = blockIdx.x & 7;
  const int rem = blockIdx.x >> 3;   // 0..39
  const int k = rem >> 2;
  const int d = (rem & 3) * 64 + threadIdx.x;
  const float4* xc = (const float4*)(xT + ((size_t)b * 256 + d) * 4096);
  const int4* ac = (const int4*)(assign + b * 4096);

  float acc = 0.0f;
  for (int c = 0; c < 64; ++c) {     // 64 chunks of 64 s
    float4 xe[16]; int4 ar[16];
#pragma unroll
    for (int j = 0; j < 16; ++j) xe[j] = xc[c * 16 + j];
#pragma unroll
    for (int j = 0; j < 16; ++j) ar[j] = ac[c * 16 + j];
#pragma unroll
    for (int j = 0; j < 16; ++j) {
      acc = __fadd_rn(acc, (ar[j].x == k) ? xe[j].x : 0.0f);
      acc = __fadd_rn(acc, (ar[j].y == k) ? xe[j].y : 0.0f);
      acc = __fadd_rn(acc, (ar[j].z == k) ? xe[j].z : 0.0f);
      acc = __fadd_rn(acc, (ar[j].w == k) ? xe[j].w : 0.0f);
    }
  }
  const int cc = cnt[b * NC + k];
  cent[((size_t)(b * NC + k)) * 256 + d] = (cc == 0) ? 0.0f : __fdiv_rn(acc, (float)cc);
}

// ---------------- K6b: cluster sums fallback (r22, strided) ----------------
__global__ __launch_bounds__(64) void k_sums(const float* __restrict__ xenh,
                                             const int* __restrict__ assign,
                                             const int* __restrict__ cnt,
                                             float* __restrict__ cent) {
  const int b = blockIdx.x & 7;
  const int rem = blockIdx.x >> 3;   // 0..39
  const int k = rem >> 2;
  const int d = (rem & 3) * 64 + threadIdx.x;
  const float* xb = xenh + (size_t)b * 4096 * 256 + d;
  const int* ab = assign + b * 4096;

  float acc = 0.0f;
  for (int c = 0; c < 64; ++c) {
    float xe[64]; int ar[64];
#pragma unroll
    for (int j = 0; j < 64; ++j) xe[j] = xb[(size_t)(c * 64 + j) * 256];
#pragma unroll
    for (int j = 0; j < 64; ++j) ar[j] = ab[c * 64 + j];
#pragma unroll
    for (int j = 0; j < 64; ++j)
      acc = __fadd_rn(acc, (ar[j] == k) ? xe[j] : 0.0f);
  }
  const int cc = cnt[b * NC + k];
  cent[((size_t)(b * NC + k)) * 256 + d] = (cc == 0) ? 0.0f : __fdiv_rn(acc, (float)cc);
}

// ---------------- K7: quantize ----------------
__global__ __launch_bounds__(256) void k_quant(const float* __restrict__ cent,
                                               const int* __restrict__ assign,
                                               float* __restrict__ out) {
  const int token = blockIdx.x * 4 + (threadIdx.x >> 6);
  const int l = threadIdx.x & 63;
  const int b = token >> 12;
  const int a = assign[token];
  ((float4*)out)[(size_t)token * 64 + l] =
      ((const float4*)cent)[(size_t)(b * NC + a) * 64 + l];
}

extern "C" void kernel_launch(void* const* d_in, const int* in_sizes, int n_in,
                              void* d_out, int out_size, void* d_ws, size_t ws_size,
                              hipStream_t stream) {
  const float* x = (const float*)d_in[0];      // [8,4096,256] f32
  const float* mem = (const float*)d_in[1];    // [1024,256] f32
  const int* init_idx = (const int*)d_in[2];   // [8,10] i32
  float* xenh = (float*)d_out;                 // x_enh materialized in d_out
  char* ws = (char*)d_ws;

  float* cent   = (float*)(ws);                //  81920 B
  int*   assign = (int*)  (ws + 81920);        // 131072 B
  int*   cntbuf = (int*)  (ws + 212992);       // KITERS*8*NC ints
  float* xT     = (float*)(ws + (1 << 20));    // 32 MB (only if ws big enough)
  const bool useT = ws_size >= ((size_t)34 << 20);

  (void)hipFuncSetAttribute((const void*)k_enh,
                            hipFuncAttributeMaxDynamicSharedMemorySize, 131072);

  k_zero<<<4, 256, 0, stream>>>(cntbuf, KITERS * 8 * NC);
  k_enh<<<512, 256, 131072, stream>>>(x, mem, xenh);
  if (useT) k_transpose_x<<<dim3(128, 8, 8), 256, 0, stream>>>(xenh, xT);
  k_init<<<80, 64, 0, stream>>>(xenh, init_idx, cent);
  for (int it = 0; it < KITERS; ++it) {
    k_assign<<<256, 256, 0, stream>>>(xenh, cent, assign, cntbuf + it * 8 * NC);
    if (useT)
      k_sums_T<<<320, 64, 0, stream>>>(xT, assign, cntbuf + it * 8 * NC, cent);
    else
      k_sums<<<320, 64, 0, stream>>>(xenh, assign, cntbuf + it * 8 * NC, cent);
  }
  k_quant<<<8192, 256, 0, stream>>>(cent, assign, (float*)d_out);
}